// Round 7
// baseline (574.308 us; speedup 1.0000x reference)
//
#include <hip/hip_runtime.h>

// EmotionCaps dynamic routing (fp32 I/O):
// u: [B=64, N=1024, I=64] f32; W: [N=1024, E=8, O=32, I=64] f32
// out: v [B=64, E=8, O=32] f32
// Stage 1 (k_uhat): u_hat (bf16, 32MB ws) = per-n GEMM via bf16 MFMA
//          (block 0 also zeroes s/cnt). ~35us, HBM-ish bound.
// Stage 2: 3x k_route_s at 2048 blocks (full chip), squash fused via
//          last-block-per-b counter pattern (round-3 grid.sync = 110us/sync
//          and round-6 64-block fusion = 87us both measured dead ends).
//          Logit identity: b1 = uh.v0 ; b2 = uh.(v0+v1) — no logit storage.

#define B_  64
#define N_  1024
#define I_  64
#define E_  8
#define O_  32
#define EO_ 256
#define PAD_ 72

typedef __bf16 bf16x8 __attribute__((ext_vector_type(8)));
typedef __bf16 bf16x4v __attribute__((ext_vector_type(4)));
typedef float  f32x4  __attribute__((ext_vector_type(4)));

__device__ __forceinline__ float bf2f(unsigned int h) {
    unsigned int x = (h & 0xffffu) << 16;
    return __builtin_bit_cast(float, x);
}
__device__ __forceinline__ unsigned short f2bf(float f) {
    unsigned int x = __builtin_bit_cast(unsigned int, f);
    unsigned int r = x + 0x7fffu + ((x >> 16) & 1u);   // RNE
    return (unsigned short)(r >> 16);
}
__device__ __forceinline__ void cvt_store4(unsigned short* dst, float4 q) {
    bf16x4v v;
    v[0] = (__bf16)q.x; v[1] = (__bf16)q.y; v[2] = (__bf16)q.z; v[3] = (__bf16)q.w;
    *(bf16x4v*)dst = v;
}
__device__ __forceinline__ bf16x8 cvt8(const float* __restrict__ p) {
    float4 q0 = *(const float4*)p;
    float4 q1 = *(const float4*)(p + 4);
    bf16x8 a;
    a[0] = (__bf16)q0.x; a[1] = (__bf16)q0.y; a[2] = (__bf16)q0.z; a[3] = (__bf16)q0.w;
    a[4] = (__bf16)q1.x; a[5] = (__bf16)q1.y; a[6] = (__bf16)q1.z; a[7] = (__bf16)q1.w;
    return a;
}

// ---------------------------------------------------------------------------
// K1: one block per n. D[64b x 256eo] = u[:,n,:] . W[n]^T via 16x16x32 bf16
// MFMA (fragment layouts verified rounds 3-6). u staged in LDS (A-frags);
// W frags streamed from global; D transposed through LDS for coalesced stores.
// Block 0 additionally zeroes s (16K floats) and cnt (192 ints).
// ---------------------------------------------------------------------------
__global__ __launch_bounds__(256) void k_uhat(const float* __restrict__ u,
                                              const float* __restrict__ W,
                                              unsigned short* __restrict__ uh,
                                              float* __restrict__ s,
                                              int* __restrict__ cnt) {
    const int n = blockIdx.x;
    const int t = threadIdx.x;
    const int w = t >> 6, l = t & 63;
    const int m16 = l & 15, g = l >> 4;

    if (n == 0) {
#pragma unroll
        for (int i = 0; i < 64; ++i) s[i * 256 + t] = 0.f;
        if (t < 192) cnt[t] = 0;
    }

    __shared__ __align__(16) unsigned short ul[B_ * PAD_];      //  9216 B
    __shared__ __align__(16) unsigned short Dt[B_ * 264];       // 33792 B

#pragma unroll
    for (int j = 0; j < 4; ++j) {
        int idx = j * 256 + t;
        int b = idx >> 4, c = idx & 15;
        float4 q = *(const float4*)(u + (size_t)b * (N_ * I_) + n * I_ + c * 4);
        cvt_store4(&ul[b * PAD_ + c * 4], q);
    }
    __syncthreads();

    bf16x8 afr[4][2];   // A[m=lane&15][k=(lane>>4)*8+j]
#pragma unroll
    for (int mt = 0; mt < 4; ++mt)
#pragma unroll
        for (int ks = 0; ks < 2; ++ks)
            afr[mt][ks] = *(const bf16x8*)&ul[(mt * 16 + m16) * PAD_ + ks * 32 + g * 8];

    f32x4 acc[4][4];
#pragma unroll
    for (int nt = 0; nt < 4; ++nt)
#pragma unroll
        for (int mt = 0; mt < 4; ++mt)
            acc[nt][mt] = (f32x4){0.f, 0.f, 0.f, 0.f};

    const float* Wn = W + (size_t)n * (EO_ * I_);
#pragma unroll
    for (int nt = 0; nt < 4; ++nt) {
        const int eo = w * 64 + nt * 16 + m16;
        const float* wp = Wn + (size_t)eo * I_ + g * 8;
        bf16x8 b0 = cvt8(wp);
        bf16x8 b1 = cvt8(wp + 32);
#pragma unroll
        for (int mt = 0; mt < 4; ++mt) {
            acc[nt][mt] = __builtin_amdgcn_mfma_f32_16x16x32_bf16(afr[mt][0], b0, acc[nt][mt], 0, 0, 0);
            acc[nt][mt] = __builtin_amdgcn_mfma_f32_16x16x32_bf16(afr[mt][1], b1, acc[nt][mt], 0, 0, 0);
        }
    }

    // D lane map: col=lane&15, row=(lane>>4)*4+reg -> LDS transpose
#pragma unroll
    for (int nt = 0; nt < 4; ++nt) {
        const int col = w * 64 + nt * 16 + m16;
#pragma unroll
        for (int mt = 0; mt < 4; ++mt)
#pragma unroll
            for (int r = 0; r < 4; ++r)
                Dt[(mt * 16 + g * 4 + r) * 264 + col] = f2bf(acc[nt][mt][r]);
    }
    __syncthreads();
#pragma unroll
    for (int r = 0; r < 16; ++r) {
        const int row = r * 4 + w;
        uint2 q = *(const uint2*)&Dt[row * 264 + l * 4];
        *(uint2*)(uh + (size_t)row * (N_ * EO_) + (size_t)n * EO_ + l * 4) = q;
    }
}

// ---------------------------------------------------------------------------
// K2: one routing pass + fused squash. 2048 blocks = (b, chunk of 32 n);
// wave handles 8 n; lane l owns eo = 4l..4l+3 (e = l>>3). Shuffle math
// verified rounds 2-6: dot over o = shfl 1,2,4; softmax over E = shfl 8,16,32.
// Partials: LDS reduce -> 1 atomicAdd per (b,eo) per block into s.
// Last block per (it,b) (counter): fence, coherent re-read of s (atomic RMW),
// squash over o, update vsum/vwork/out, re-zero s for the next pass.
// it0: c=1/8, vsum=vwork=v0. it1: logit=uh.v0, vwork=v0+v1. it2: out=v2.
// ---------------------------------------------------------------------------
__global__ __launch_bounds__(256) void k_route_s(const unsigned short* __restrict__ uh,
                                                 float* __restrict__ vwork,
                                                 float* __restrict__ vsum,
                                                 float* __restrict__ s,
                                                 int* __restrict__ cnt,
                                                 float* __restrict__ out,
                                                 int it) {
    const int blk = blockIdx.x;
    const int b = blk >> 5, chunk = blk & 31;
    const int t = threadIdx.x, wave = t >> 6, l = t & 63;

    const unsigned short* base = uh + (size_t)b * (N_ * EO_)
                                    + (size_t)(chunk * 32 + wave * 8) * EO_ + 4 * l;
    float x[8][4];
    float c[8];

    if (it == 0) {
#pragma unroll
        for (int nn = 0; nn < 8; ++nn) {
            uint2 p = *(const uint2*)(base + nn * EO_);
            x[nn][0] = bf2f(p.x); x[nn][1] = bf2f(p.x >> 16);
            x[nn][2] = bf2f(p.y); x[nn][3] = bf2f(p.y >> 16);
            c[nn] = 0.125f;
        }
    } else {
        float4 v4 = *(const float4*)(vwork + b * EO_ + 4 * l);
        float lg[8];
#pragma unroll
        for (int nn = 0; nn < 8; ++nn) {          // independent chains
            uint2 p = *(const uint2*)(base + nn * EO_);
            x[nn][0] = bf2f(p.x); x[nn][1] = bf2f(p.x >> 16);
            x[nn][2] = bf2f(p.y); x[nn][3] = bf2f(p.y >> 16);
            float pd = x[nn][0] * v4.x + x[nn][1] * v4.y
                     + x[nn][2] * v4.z + x[nn][3] * v4.w;
            pd += __shfl_xor(pd, 1);
            pd += __shfl_xor(pd, 2);
            pd += __shfl_xor(pd, 4);              // logit(n,e) in all 8 e-lanes
            lg[nn] = pd;
        }
        float mx[8];
#pragma unroll
        for (int nn = 0; nn < 8; ++nn) mx[nn] = lg[nn];
#pragma unroll
        for (int nn = 0; nn < 8; ++nn) mx[nn] = fmaxf(mx[nn], __shfl_xor(mx[nn], 8));
#pragma unroll
        for (int nn = 0; nn < 8; ++nn) mx[nn] = fmaxf(mx[nn], __shfl_xor(mx[nn], 16));
#pragma unroll
        for (int nn = 0; nn < 8; ++nn) mx[nn] = fmaxf(mx[nn], __shfl_xor(mx[nn], 32));
        float ex[8], sm[8];
#pragma unroll
        for (int nn = 0; nn < 8; ++nn) { ex[nn] = __expf(lg[nn] - mx[nn]); sm[nn] = ex[nn]; }
#pragma unroll
        for (int nn = 0; nn < 8; ++nn) sm[nn] += __shfl_xor(sm[nn], 8);
#pragma unroll
        for (int nn = 0; nn < 8; ++nn) sm[nn] += __shfl_xor(sm[nn], 16);
#pragma unroll
        for (int nn = 0; nn < 8; ++nn) sm[nn] += __shfl_xor(sm[nn], 32);
#pragma unroll
        for (int nn = 0; nn < 8; ++nn) c[nn] = ex[nn] * __builtin_amdgcn_rcpf(sm[nn]);
    }

    float a0 = 0.f, a1 = 0.f, a2 = 0.f, a3 = 0.f;
#pragma unroll
    for (int nn = 0; nn < 8; ++nn) {
        a0 = fmaf(c[nn], x[nn][0], a0); a1 = fmaf(c[nn], x[nn][1], a1);
        a2 = fmaf(c[nn], x[nn][2], a2); a3 = fmaf(c[nn], x[nn][3], a3);
    }

    __shared__ __align__(16) float red[4][EO_];
    __shared__ int lastf;
    *(float4*)&red[wave][4 * l] = make_float4(a0, a1, a2, a3);
    __syncthreads();
    atomicAdd(&s[b * EO_ + t], red[0][t] + red[1][t] + red[2][t] + red[3][t]);
    __threadfence();                      // release: my add globally visible
    __syncthreads();                      // all 256 adds+fences done
    if (t == 0) lastf = (atomicAdd(&cnt[it * 64 + b], 1) == 31);
    __syncthreads();
    if (lastf) {
        __threadfence();                  // acquire
        float sv = atomicAdd(&s[b * EO_ + t], 0.f);   // coherent read (RMW)
        float sq = sv * sv;
        sq += __shfl_xor(sq, 1);
        sq += __shfl_xor(sq, 2);
        sq += __shfl_xor(sq, 4);
        sq += __shfl_xor(sq, 8);
        sq += __shfl_xor(sq, 16);         // |s|^2 over o-group (t=eo, o=t&31)
        float nrm = sqrtf(sq);
        float vv = sq / ((1.f + sq) * (nrm + 1e-8f)) * sv;
        s[b * EO_ + t] = 0.f;             // re-zero for next pass
        if (it == 0)      { vsum[b * EO_ + t] = vv; vwork[b * EO_ + t] = vv; }
        else if (it == 1) { vwork[b * EO_ + t] = vsum[b * EO_ + t] + vv; }
        else              { out[b * EO_ + t] = vv; }
    }
}

extern "C" void kernel_launch(void* const* d_in, const int* in_sizes, int n_in,
                              void* d_out, int out_size, void* d_ws, size_t ws_size,
                              hipStream_t stream) {
    const float* u = (const float*)d_in[0];     // f32 [64,1024,64]
    const float* W = (const float*)d_in[1];     // f32 [1024,8,32,64]
    float* out = (float*)d_out;                 // f32 [64,8,32]

    char* ws = (char*)d_ws;
    unsigned short* uh = (unsigned short*)ws;    // 33,554,432 B  u_hat bf16
    float* s     = (float*)(ws + 33554432);      // 65,536 B
    float* vsum  = (float*)(ws + 33619968);      // 65,536 B
    float* vwork = (float*)(ws + 33685504);      // 65,536 B
    int*   cnt   = (int*)  (ws + 33751040);      //    768 B

    k_uhat   <<<dim3(N_),   dim3(256), 0, stream>>>(u, W, uh, s, cnt);
    k_route_s<<<dim3(2048), dim3(256), 0, stream>>>(uh, vwork, vsum, s, cnt, out, 0);
    k_route_s<<<dim3(2048), dim3(256), 0, stream>>>(uh, vwork, vsum, s, cnt, out, 1);
    k_route_s<<<dim3(2048), dim3(256), 0, stream>>>(uh, vwork, vsum, s, cnt, out, 2);
}

// Round 8
// 135.539 us; speedup vs baseline: 4.2372x; 4.2372x over previous
//
#include <hip/hip_runtime.h>

// EmotionCaps dynamic routing (fp32 I/O):
// u: [B=64, N=1024, I=64] f32; W: [N=1024, E=8, O=32, I=64] f32
// out: v [B=64, E=8, O=32] f32
//
// Structure (5 dispatches — kernel boundaries are the only cross-block sync;
// measured dead ends: grid.sync 110us/sync (r3), 64-block fusion 87us (r6),
// threadfence+counter 190us/pass (r7)):
//   k_uhat   : u_hat bf16 (32MB ws) via 16x16x32 bf16 MFMA; zeroes s0/s1/s2.
//   k_route 0: c=1/8            -> atomicAdd s0   (plain atomics: r2-proven)
//   k_route 1: v0=squash(s0)    -> logits=uh.v0   -> atomicAdd s1
//   k_route 2: v01=v0+v1        -> logits=uh.v01  -> atomicAdd s2
//   k_out    : out = squash(s2)
// Logit identity b2 = uh.(v0+v1) verified rounds 4-7 (absmax stable 0.0039).

#define B_  64
#define N_  1024
#define I_  64
#define E_  8
#define O_  32
#define EO_ 256
#define PAD_ 72

typedef __bf16 bf16x8 __attribute__((ext_vector_type(8)));
typedef __bf16 bf16x4v __attribute__((ext_vector_type(4)));
typedef float  f32x4  __attribute__((ext_vector_type(4)));

__device__ __forceinline__ float bf2f(unsigned int h) {
    unsigned int x = (h & 0xffffu) << 16;
    return __builtin_bit_cast(float, x);
}
__device__ __forceinline__ void cvt_store4(unsigned short* dst, float4 q) {
    bf16x4v v;
    v[0] = (__bf16)q.x; v[1] = (__bf16)q.y; v[2] = (__bf16)q.z; v[3] = (__bf16)q.w;
    *(bf16x4v*)dst = v;
}
__device__ __forceinline__ bf16x8 cvt8(const float* __restrict__ p) {
    float4 q0 = *(const float4*)p;
    float4 q1 = *(const float4*)(p + 4);
    bf16x8 a;
    a[0] = (__bf16)q0.x; a[1] = (__bf16)q0.y; a[2] = (__bf16)q0.z; a[3] = (__bf16)q0.w;
    a[4] = (__bf16)q1.x; a[5] = (__bf16)q1.y; a[6] = (__bf16)q1.z; a[7] = (__bf16)q1.w;
    return a;
}
// squash over the 32-elem o-group; lane l holds s[4l..4l+3] of its e-group
// (8 lanes x 4). shfl 1,2,4 stays inside the 8-lane e-group.
__device__ __forceinline__ float4 squash4(float4 s4) {
    float sq = s4.x * s4.x + s4.y * s4.y + s4.z * s4.z + s4.w * s4.w;
    sq += __shfl_xor(sq, 1);
    sq += __shfl_xor(sq, 2);
    sq += __shfl_xor(sq, 4);
    float nrm = sqrtf(sq);
    float sc = sq / ((1.f + sq) * (nrm + 1e-8f));
    return make_float4(sc * s4.x, sc * s4.y, sc * s4.z, sc * s4.w);
}

// ---------------------------------------------------------------------------
// K1: one block per n. D[64b x 256eo] = u[:,n,:] . W[n]^T via 16x16x32 bf16
// MFMA (fragment layouts verified rounds 3-7). u staged in LDS (A-frags);
// W frags streamed from global; D transposed through the SAME LDS buffer
// (union: 33792 B -> 4 blocks/CU) for coalesced uint2 stores.
// Epilogue uses hardware bf16 casts (RNE), not manual bit-twiddling.
// Blocks 0..2 zero s0/s1/s2 (workspace is poisoned each call).
// ---------------------------------------------------------------------------
__global__ __launch_bounds__(256) void k_uhat(const float* __restrict__ u,
                                              const float* __restrict__ W,
                                              unsigned short* __restrict__ uh,
                                              float* __restrict__ s012) {
    const int n = blockIdx.x;
    const int t = threadIdx.x;
    const int w = t >> 6, l = t & 63;
    const int m16 = l & 15, g = l >> 4;

    if (n < 3) {
        float* sz = s012 + n * (B_ * EO_);
#pragma unroll
        for (int i = 0; i < 64; ++i) sz[i * 256 + t] = 0.f;
    }

    __shared__ __align__(16) unsigned short sh[B_ * 264];   // 33792 B (union)
    unsigned short* ul = sh;        // phase 1: u tile [B_][PAD_]
    unsigned short* Dt = sh;        // phase 2: D tile [B_][264]

#pragma unroll
    for (int j = 0; j < 4; ++j) {
        int idx = j * 256 + t;
        int b = idx >> 4, c = idx & 15;
        float4 q = *(const float4*)(u + (size_t)b * (N_ * I_) + n * I_ + c * 4);
        cvt_store4(&ul[b * PAD_ + c * 4], q);
    }
    __syncthreads();

    bf16x8 afr[4][2];   // A[m=lane&15][k=(lane>>4)*8+j]
#pragma unroll
    for (int mt = 0; mt < 4; ++mt)
#pragma unroll
        for (int ks = 0; ks < 2; ++ks)
            afr[mt][ks] = *(const bf16x8*)&ul[(mt * 16 + m16) * PAD_ + ks * 32 + g * 8];
    __syncthreads();    // all waves done reading ul; sh now reusable as Dt

    f32x4 acc[4][4];
#pragma unroll
    for (int nt = 0; nt < 4; ++nt)
#pragma unroll
        for (int mt = 0; mt < 4; ++mt)
            acc[nt][mt] = (f32x4){0.f, 0.f, 0.f, 0.f};

    const float* Wn = W + (size_t)n * (EO_ * I_);
#pragma unroll
    for (int nt = 0; nt < 4; ++nt) {
        const int eo = w * 64 + nt * 16 + m16;
        const float* wp = Wn + (size_t)eo * I_ + g * 8;
        bf16x8 b0 = cvt8(wp);
        bf16x8 b1 = cvt8(wp + 32);
#pragma unroll
        for (int mt = 0; mt < 4; ++mt) {
            acc[nt][mt] = __builtin_amdgcn_mfma_f32_16x16x32_bf16(afr[mt][0], b0, acc[nt][mt], 0, 0, 0);
            acc[nt][mt] = __builtin_amdgcn_mfma_f32_16x16x32_bf16(afr[mt][1], b1, acc[nt][mt], 0, 0, 0);
        }
    }

    // D lane map: col=lane&15, row=(lane>>4)*4+reg -> LDS transpose (hw cvt)
#pragma unroll
    for (int nt = 0; nt < 4; ++nt) {
        const int col = w * 64 + nt * 16 + m16;
#pragma unroll
        for (int mt = 0; mt < 4; ++mt)
#pragma unroll
            for (int r = 0; r < 4; ++r) {
                __bf16 hv = (__bf16)acc[nt][mt][r];
                Dt[(mt * 16 + g * 4 + r) * 264 + col] =
                    __builtin_bit_cast(unsigned short, hv);
            }
    }
    __syncthreads();
#pragma unroll
    for (int r = 0; r < 16; ++r) {
        const int row = r * 4 + w;
        uint2 q = *(const uint2*)&Dt[row * 264 + l * 4];
        *(uint2*)(uh + (size_t)row * (N_ * EO_) + (size_t)n * EO_ + l * 4) = q;
    }
}

// ---------------------------------------------------------------------------
// K2: one routing pass. 2048 blocks = (b, chunk of 32 n); wave handles 8 n;
// lane l owns eo = 4l..4l+3 (e = l>>3). Shuffle math verified rounds 2-7:
// dot over o = shfl 1,2,4; softmax over E = shfl 8,16,32.
// it selects the v recomputation (from s0/s1, visible since prior dispatch
// completed) and the target accumulator. One atomicAdd per (b,eo) per block.
// ---------------------------------------------------------------------------
__global__ __launch_bounds__(256) void k_route(const unsigned short* __restrict__ uh,
                                               const float* __restrict__ s0,
                                               const float* __restrict__ s1,
                                               float* __restrict__ tgt,
                                               int it) {
    const int blk = blockIdx.x;
    const int b = blk >> 5, chunk = blk & 31;
    const int t = threadIdx.x, wave = t >> 6, l = t & 63;

    const unsigned short* base = uh + (size_t)b * (N_ * EO_)
                                    + (size_t)(chunk * 32 + wave * 8) * EO_ + 4 * l;
    float x[8][4];
    float c[8];

    if (it == 0) {
#pragma unroll
        for (int nn = 0; nn < 8; ++nn) {
            uint2 p = *(const uint2*)(base + nn * EO_);
            x[nn][0] = bf2f(p.x); x[nn][1] = bf2f(p.x >> 16);
            x[nn][2] = bf2f(p.y); x[nn][3] = bf2f(p.y >> 16);
            c[nn] = 0.125f;
        }
    } else {
        // recompute v (and v0+v1 for it==2) from s-buffers: ~20 VALU, L2-hot
        float4 v4 = squash4(*(const float4*)(s0 + b * EO_ + 4 * l));
        if (it == 2) {
            float4 v1 = squash4(*(const float4*)(s1 + b * EO_ + 4 * l));
            v4.x += v1.x; v4.y += v1.y; v4.z += v1.z; v4.w += v1.w;
        }
        float lg[8];
#pragma unroll
        for (int nn = 0; nn < 8; ++nn) {
            uint2 p = *(const uint2*)(base + nn * EO_);
            x[nn][0] = bf2f(p.x); x[nn][1] = bf2f(p.x >> 16);
            x[nn][2] = bf2f(p.y); x[nn][3] = bf2f(p.y >> 16);
            float pd = x[nn][0] * v4.x + x[nn][1] * v4.y
                     + x[nn][2] * v4.z + x[nn][3] * v4.w;
            pd += __shfl_xor(pd, 1);
            pd += __shfl_xor(pd, 2);
            pd += __shfl_xor(pd, 4);              // logit(n,e) in all 8 e-lanes
            lg[nn] = pd;
        }
        float mx[8];
#pragma unroll
        for (int nn = 0; nn < 8; ++nn) mx[nn] = lg[nn];
#pragma unroll
        for (int nn = 0; nn < 8; ++nn) mx[nn] = fmaxf(mx[nn], __shfl_xor(mx[nn], 8));
#pragma unroll
        for (int nn = 0; nn < 8; ++nn) mx[nn] = fmaxf(mx[nn], __shfl_xor(mx[nn], 16));
#pragma unroll
        for (int nn = 0; nn < 8; ++nn) mx[nn] = fmaxf(mx[nn], __shfl_xor(mx[nn], 32));
        float ex[8], sm[8];
#pragma unroll
        for (int nn = 0; nn < 8; ++nn) { ex[nn] = __expf(lg[nn] - mx[nn]); sm[nn] = ex[nn]; }
#pragma unroll
        for (int nn = 0; nn < 8; ++nn) sm[nn] += __shfl_xor(sm[nn], 8);
#pragma unroll
        for (int nn = 0; nn < 8; ++nn) sm[nn] += __shfl_xor(sm[nn], 16);
#pragma unroll
        for (int nn = 0; nn < 8; ++nn) sm[nn] += __shfl_xor(sm[nn], 32);
#pragma unroll
        for (int nn = 0; nn < 8; ++nn) c[nn] = ex[nn] * __builtin_amdgcn_rcpf(sm[nn]);
    }

    float a0 = 0.f, a1 = 0.f, a2 = 0.f, a3 = 0.f;
#pragma unroll
    for (int nn = 0; nn < 8; ++nn) {
        a0 = fmaf(c[nn], x[nn][0], a0); a1 = fmaf(c[nn], x[nn][1], a1);
        a2 = fmaf(c[nn], x[nn][2], a2); a3 = fmaf(c[nn], x[nn][3], a3);
    }

    __shared__ __align__(16) float red[4][EO_];
    *(float4*)&red[wave][4 * l] = make_float4(a0, a1, a2, a3);
    __syncthreads();
    atomicAdd(&tgt[b * EO_ + t], red[0][t] + red[1][t] + red[2][t] + red[3][t]);
}

// ---------------------------------------------------------------------------
// K3: out = squash(s2). 64 blocks x 256 (t = eo; o-group = 32 lanes).
// ---------------------------------------------------------------------------
__global__ __launch_bounds__(256) void k_out(const float* __restrict__ s2,
                                             float* __restrict__ out) {
    const int b = blockIdx.x, t = threadIdx.x;
    float sv = s2[b * EO_ + t];
    float sq = sv * sv;
    sq += __shfl_xor(sq, 1);
    sq += __shfl_xor(sq, 2);
    sq += __shfl_xor(sq, 4);
    sq += __shfl_xor(sq, 8);
    sq += __shfl_xor(sq, 16);
    float nrm = sqrtf(sq);
    out[b * EO_ + t] = sq / ((1.f + sq) * (nrm + 1e-8f)) * sv;
}

extern "C" void kernel_launch(void* const* d_in, const int* in_sizes, int n_in,
                              void* d_out, int out_size, void* d_ws, size_t ws_size,
                              hipStream_t stream) {
    const float* u = (const float*)d_in[0];     // f32 [64,1024,64]
    const float* W = (const float*)d_in[1];     // f32 [1024,8,32,64]
    float* out = (float*)d_out;                 // f32 [64,8,32]

    char* ws = (char*)d_ws;
    unsigned short* uh = (unsigned short*)ws;    // 33,554,432 B  u_hat bf16
    float* s0 = (float*)(ws + 33554432);         // 65,536 B
    float* s1 = (float*)(ws + 33620 * 1024);     // (33620*1024 = 34,426,880)
    float* s2 = (float*)(ws + 34492416);         // 65,536 B

    // contiguous s0|s1|s2 for the zeroing loop in k_uhat
    s1 = s0 + B_ * EO_;
    s2 = s1 + B_ * EO_;

    k_uhat <<<dim3(N_),   dim3(256), 0, stream>>>(u, W, uh, s0);
    k_route<<<dim3(2048), dim3(256), 0, stream>>>(uh, s0, s1, s0, 0);
    k_route<<<dim3(2048), dim3(256), 0, stream>>>(uh, s0, s1, s1, 1);
    k_route<<<dim3(2048), dim3(256), 0, stream>>>(uh, s0, s1, s2, 2);
    k_out  <<<dim3(B_),   dim3(256), 0, stream>>>(s2, out);
}